// Round 11
// baseline (1314.913 us; speedup 1.0000x reference)
//
#include <hip/hip_runtime.h>
#include <cstddef>

#define NSP   56
#define NPX   3136
#define CINN  32
#define COUTN 64
#define NB    128
#define CO_PB 8
#define THR   448            // 7 waves; 448 * 7 iters = 3136 pixels exactly
#define NIT   7

typedef int v4i __attribute__((ext_vector_type(4)));

__device__ float llvm_amdgcn_raw_buffer_load_f32(v4i rsrc, int voffset, int soffset, int aux)
    __asm("llvm.amdgcn.raw.buffer.load.f32");
__device__ void llvm_amdgcn_raw_buffer_store_f32(float data, v4i rsrc, int voffset, int soffset, int aux)
    __asm("llvm.amdgcn.raw.buffer.store.f32");

__device__ inline v4i make_rsrc(const void* p, int nbytes)
{
    union { const void* p; unsigned u[2]; } a; a.p = p;
    v4i r;
    r[0] = (int)a.u[0];
    r[1] = (int)a.u[1];      // stride=0, base[47:32]
    r[2] = nbytes;           // num_records (bytes)
    r[3] = 0x00020000;       // raw dword buffer
    return r;
}

// ---- pass 0: transpose W [co][c][kh][kw] -> w2 [cog][kk][c][co8] ----
__global__ __launch_bounds__(256)
void wtrans(const float* __restrict__ W, float* __restrict__ w2)
{
    int idx = blockIdx.x * 256 + threadIdx.x;
    if (idx < COUTN * CINN * 9) {
        int co_l = idx & 7;
        int t    = idx >> 3;         // (cog*9 + kk)*32 + c
        int c    = t & 31;
        t >>= 5;                     // cog*9 + kk
        int kk   = t % 9;
        int cog  = t / 9;
        w2[idx] = W[(size_t)(cog * 8 + co_l) * (CINN * 9) + c * 9 + kk];
    }
}

// ---- pass 1: conv(+bias,relu) in XLA:CPU/Eigen rounding order, y + argmax ----
// One pixel per thread per iteration. NO LDS in the hot loop: x via
// bounds-checked buffer loads (vmcnt), weights via s_load (lgkmcnt, now
// unshared with any ds traffic -> cheap waits). OOB terms cndmask'd to 0 =
// exact no-op FMAs, identical to the reference's zero padding.
__global__ __launch_bounds__(THR, 2)
void conv_px(const float* __restrict__ x,
             const float* __restrict__ w2,   // [8][9][32][8]
             const float* __restrict__ bias,
             float* __restrict__ y,          // d_out: relu(conv+bias)
             int* __restrict__ amax)         // [NB*COUTN] argmax idx
{
    __shared__ float rvs[7][CO_PB];
    __shared__ int   ris[7][CO_PB];

    const int tid = threadIdx.x;
    const int ty  = tid >> 6;          // wave 0..6
    const int b       = blockIdx.x >> 3;
    const int cog     = blockIdx.x & 7;
    const int co_base = cog * CO_PB;

    const float* xb = x  + (size_t)b * CINN * NPX;
    const float* wq = w2 + (size_t)cog * (9 * CINN * CO_PB);   // uniform
    float* yo = y + (size_t)(b * COUTN + co_base) * NPX;

    const v4i rx = make_rsrc(xb, CINN * NPX * 4);
    const v4i ry = make_rsrc(yo, CO_PB * NPX * 4);

    float bs[CO_PB];
    #pragma unroll
    for (int co = 0; co < CO_PB; ++co) bs[co] = bias[co_base + co];

    float v1[CO_PB]; int i1[CO_PB];
    #pragma unroll
    for (int co = 0; co < CO_PB; ++co) { v1[co] = -1.f; i1[co] = 0; }

    #pragma unroll 1
    for (int it = 0; it < NIT; ++it) {
        const int p   = it * THR + tid;          // ascending per thread
        const int row = p / NSP;
        const int col = p - row * NSP;
        const bool cL = (col > 0);
        const bool cR = (col < NSP - 1);

        float acc[CO_PB];
        #pragma unroll
        for (int co = 0; co < CO_PB; ++co) acc[co] = 0.f;

        // EXACT ref rounding order: kh -> kw -> c (c innermost), single f32
        // acc, fmaf per term; OOB terms are exact zeros.
        #pragma unroll
        for (int kh = 0; kh < 3; ++kh) {
            const int  r  = row + kh - 1;
            const bool rv = ((unsigned)r < (unsigned)NSP);
            const int  voff = (r * NSP + col) * 4;    // may be "negative" -> OOB ret 0

            float xm[CINN], xc[CINN], xp_[CINN];
            #pragma unroll
            for (int c = 0; c < CINN; ++c) {
                const int so = c * (NPX * 4);         // uniform soffset per channel
                float a = llvm_amdgcn_raw_buffer_load_f32(rx, voff - 4, so, 0);
                float m = llvm_amdgcn_raw_buffer_load_f32(rx, voff,     so, 0);
                float d = llvm_amdgcn_raw_buffer_load_f32(rx, voff + 4, so, 0);
                xm[c]  = (rv && cL) ? a : 0.f;
                xc[c]  =  rv        ? m : 0.f;
                xp_[c] = (rv && cR) ? d : 0.f;
            }
            #pragma unroll
            for (int kw = 0; kw < 3; ++kw) {
                const float* wk = wq + (kh * 3 + kw) * (CINN * CO_PB);  // uniform
                #pragma unroll
                for (int c = 0; c < CINN; ++c) {
                    const float xv = (kw == 0) ? xm[c] : (kw == 1) ? xc[c] : xp_[c];
                    #pragma unroll
                    for (int co = 0; co < CO_PB; ++co)
                        acc[co] = fmaf(xv, wk[c * CO_PB + co], acc[co]);
                }
            }
        }

        #pragma unroll
        for (int co = 0; co < CO_PB; ++co) {
            float v = acc[co] + bs[co];               // separate f32 bias add
            v = fmaxf(v, 0.f);                        // relu
            llvm_amdgcn_raw_buffer_store_f32(v, ry, p * 4, co * (NPX * 4), 0);
            if (v > v1[co]) { v1[co] = v; i1[co] = p; }   // strict > = first idx
        }
    }

    // block argmax per co: lexicographic (max val, min idx)
    #pragma unroll
    for (int co = 0; co < CO_PB; ++co) {
        float bv = v1[co]; int bi = i1[co];
        #pragma unroll
        for (int off = 32; off > 0; off >>= 1) {
            float ov = __shfl_xor(bv, off);
            int   oi = __shfl_xor(bi, off);
            if (ov > bv || (ov == bv && oi < bi)) { bv = ov; bi = oi; }
        }
        if ((tid & 63) == 0) { rvs[ty][co] = bv; ris[ty][co] = bi; }
    }
    __syncthreads();
    if (tid < CO_PB) {
        float bv = rvs[0][tid]; int bi = ris[0][tid];
        #pragma unroll
        for (int w = 1; w < 7; ++w) {
            float ov = rvs[w][tid]; int oi = ris[w][tid];
            if (ov > bv || (ov == bv && oi < bi)) { bv = ov; bi = oi; }
        }
        amax[b * COUTN + co_base + tid] = bi;
    }
}

// ---- pass 2: in-place mask apply using the real templates input ----
__global__ __launch_bounds__(256)
void mask_apply_pass2(float* __restrict__ y,
                      const float* __restrict__ tmpl,
                      const int* __restrict__ amax)
{
    const int bc = blockIdx.x;                    // (b*64+co)
    const int idx = amax[bc];
    const float4* tp = (const float4*)(tmpl + (size_t)idx * NPX);
    float4* yp = (float4*)(y + (size_t)bc * NPX);
    #pragma unroll 1
    for (int p = threadIdx.x; p < NPX / 4; p += 256) {
        float4 a = yp[p];
        float4 t = tp[p];
        a.x *= t.x; a.y *= t.y; a.z *= t.z; a.w *= t.w;
        a.x = a.x > 0.f ? a.x : 0.f;
        a.y = a.y > 0.f ? a.y : 0.f;
        a.z = a.z > 0.f ? a.z : 0.f;
        a.w = a.w > 0.f ? a.w : 0.f;
        yp[p] = a;
    }
}

extern "C" void kernel_launch(void* const* d_in, const int* in_sizes, int n_in,
                              void* d_out, int out_size, void* d_ws, size_t ws_size,
                              hipStream_t stream)
{
    (void)in_sizes; (void)n_in; (void)ws_size; (void)out_size;
    const float* x  = (const float*)d_in[0];
    const float* W  = (const float*)d_in[1];
    const float* bi = (const float*)d_in[2];
    const float* tm = (const float*)d_in[3];
    float* out = (float*)d_out;
    int*   amax = (int*)d_ws;                           // 32 KB
    float* w2   = (float*)((char*)d_ws + 32768);        // 72 KB

    hipLaunchKernelGGL(wtrans, dim3(72), dim3(256), 0, stream, W, w2);

    dim3 grid1(NB * (COUTN / CO_PB));   // 1024 blocks
    hipLaunchKernelGGL(conv_px, grid1, dim3(THR), 0, stream,
                       x, w2, bi, out, amax);

    dim3 grid2(NB * COUTN);             // 8192 blocks
    hipLaunchKernelGGL(mask_apply_pass2, grid2, dim3(256), 0, stream,
                       out, tm, amax);
}

// Round 12
// 837.304 us; speedup vs baseline: 1.5704x; 1.5704x over previous
//
#include <hip/hip_runtime.h>
#include <cstddef>

#define NSP   56
#define NPX   3136
#define CINN  32
#define COUTN 64
#define NB    128
#define CO_PB 8
#define ROWS  7              // output rows per strip
#define NSTRIP 8             // 8 * 7 = 56
#define THR   448            // 7 waves; ty = wave = row-in-strip, tx<56 active
#define SROWS 9              // staged rows = ROWS + 2 halo
#define XC    58             // col 0 = zero, 1..56 = data, 57 = zero

// ---- pass 0: transpose W [co][c][kh][kw] -> w2 [cog][kk][c][co8] ----
__global__ __launch_bounds__(256)
void wtrans(const float* __restrict__ W, float* __restrict__ w2)
{
    int idx = blockIdx.x * 256 + threadIdx.x;
    if (idx < COUTN * CINN * 9) {
        int co_l = idx & 7;
        int t    = idx >> 3;         // (cog*9 + kk)*32 + c
        int c    = t & 31;
        t >>= 5;                     // cog*9 + kk
        int kk   = t % 9;
        int cog  = t / 9;
        w2[idx] = W[(size_t)(cog * 8 + co_l) * (CINN * 9) + c * 9 + kk];
    }
}

// ---- pass 1: conv(+bias,relu) in XLA:CPU/Eigen rounding order, y + argmax ----
// ALL inner-loop memory traffic is in-order ds_read (x: per-lane b32,
// weights: same-address b128 broadcast = conflict-free). No s_load / VMEM in
// the hot loop -> compiler can use counted lgkmcnt, no OOO-scalar drains.
__global__ __launch_bounds__(THR, 2)
void conv_emul_pass1(const float* __restrict__ x,
                     const float* __restrict__ w2,   // [8][9][32][8]
                     const float* __restrict__ bias,
                     float* __restrict__ y,          // d_out: relu(conv+bias)
                     int* __restrict__ amax)         // [NB*COUTN] argmax idx
{
    __shared__ float xs[SROWS][CINN][XC];     // 66816 B
    __shared__ float wl[9][CINN][CO_PB];      // 9216 B
    __shared__ float rv[7][CO_PB];
    __shared__ int   ri[7][CO_PB];

    const int tid = threadIdx.x;
    const int ty  = tid >> 6;          // wave 0..6 = output row within strip
    const int tx  = tid & 63;          // active tx<56 in compute
    const int b       = blockIdx.x >> 3;
    const int cog     = blockIdx.x & 7;
    const int co_base = cog * CO_PB;

    const float* xb = x  + (size_t)b * CINN * NPX;
    const float* wq = w2 + (size_t)cog * (9 * CINN * CO_PB);  // uniform

    // staging ownership: 448 = 32 channels x 14 float4-cols, fixed per thread
    const int sc = tid / 14;           // channel 0..31
    const int sv = tid - sc * 14;      // float4-col 0..13
    const float* xg = xb + (size_t)sc * NPX + 4 * sv;

    // one-time LDS init: weight slice + zero guard columns
    for (int t = tid; t < 9 * CINN * CO_PB / 4; t += THR)     // 576 float4
        ((float4*)wl)[t] = ((const float4*)wq)[t];
    for (int t = tid; t < SROWS * CINN * 2; t += THR) {       // cols 0 and 57
        int rr  = t / (CINN * 2);
        int rem = t - rr * (CINN * 2);
        int c   = rem >> 1;
        xs[rr][c][(rem & 1) ? 57 : 0] = 0.f;
    }

    float bs[CO_PB];
    #pragma unroll
    for (int co = 0; co < CO_PB; ++co) bs[co] = bias[co_base + co];

    float v1[CO_PB]; int i1[CO_PB];
    #pragma unroll
    for (int co = 0; co < CO_PB; ++co) { v1[co] = -1.f; i1[co] = 0; }

    float* yo = y + (size_t)(b * COUTN + co_base) * NPX;

    #pragma unroll 1
    for (int g = 0; g < NSTRIP; ++g) {
        if (g) __syncthreads();        // WAR on xs

        // stage rows 7g-1 .. 7g+7 (9 rows) into cols 1..56 (scalar ds writes,
        // compiler pairs them into ds_write2_b32; col offset 1 breaks b128)
        #pragma unroll
        for (int rr = 0; rr < SROWS; ++rr) {
            int gr = 7 * g + rr - 1;
            float4 val = make_float4(0.f, 0.f, 0.f, 0.f);
            if ((unsigned)gr < (unsigned)NSP)
                val = *(const float4*)(xg + gr * NSP);
            xs[rr][sc][1 + 4 * sv]     = val.x;
            xs[rr][sc][1 + 4 * sv + 1] = val.y;
            xs[rr][sc][1 + 4 * sv + 2] = val.z;
            xs[rr][sc][1 + 4 * sv + 3] = val.w;
        }
        __syncthreads();

        float acc[CO_PB];
        #pragma unroll
        for (int co = 0; co < CO_PB; ++co) acc[co] = 0.f;

        if (tx < NSP) {
            // EXACT ref rounding order: kh -> kw -> c (c innermost), single f32
            // acc, fmaf per term; guard cols/rows are zeros = exact no-op FMAs.
            #pragma unroll
            for (int kh = 0; kh < 3; ++kh) {
                #pragma unroll
                for (int kw = 0; kw < 3; ++kw) {
                    const int col = tx + kw;          // 0..57, always in-bounds
                    #pragma unroll
                    for (int c = 0; c < CINN; ++c) {
                        float xv = xs[ty + kh][c][col];               // b32
                        float4 wa = *(const float4*)&wl[kh * 3 + kw][c][0];  // bcast b128
                        float4 wb = *(const float4*)&wl[kh * 3 + kw][c][4];
                        acc[0] = fmaf(xv, wa.x, acc[0]);
                        acc[1] = fmaf(xv, wa.y, acc[1]);
                        acc[2] = fmaf(xv, wa.z, acc[2]);
                        acc[3] = fmaf(xv, wa.w, acc[3]);
                        acc[4] = fmaf(xv, wb.x, acc[4]);
                        acc[5] = fmaf(xv, wb.y, acc[5]);
                        acc[6] = fmaf(xv, wb.z, acc[6]);
                        acc[7] = fmaf(xv, wb.w, acc[7]);
                    }
                }
            }
            int p = (7 * g + ty) * NSP + tx;
            #pragma unroll
            for (int co = 0; co < CO_PB; ++co) {
                float v = acc[co] + bs[co];               // separate f32 add
                v = fmaxf(v, 0.f);
                yo[(size_t)co * NPX + p] = v;
                if (v > v1[co]) { v1[co] = v; i1[co] = p; }  // strict > = first idx
            }
        }
    }

    // block argmax per co: lexicographic (max val, min idx)
    #pragma unroll
    for (int co = 0; co < CO_PB; ++co) {
        float bv = v1[co]; int bi = i1[co];
        #pragma unroll
        for (int off = 32; off > 0; off >>= 1) {
            float ov = __shfl_xor(bv, off);
            int   oi = __shfl_xor(bi, off);
            if (ov > bv || (ov == bv && oi < bi)) { bv = ov; bi = oi; }
        }
        if ((tid & 63) == 0) { rv[ty][co] = bv; ri[ty][co] = bi; }
    }
    __syncthreads();
    if (tid < CO_PB) {
        float bv = rv[0][tid]; int bi = ri[0][tid];
        #pragma unroll
        for (int w = 1; w < 7; ++w) {
            float ov = rv[w][tid]; int oi = ri[w][tid];
            if (ov > bv || (ov == bv && oi < bi)) { bv = ov; bi = oi; }
        }
        amax[b * COUTN + co_base + tid] = bi;
    }
}

// ---- pass 2: in-place mask apply using the real templates input ----
__global__ __launch_bounds__(256)
void mask_apply_pass2(float* __restrict__ y,
                      const float* __restrict__ tmpl,
                      const int* __restrict__ amax)
{
    const int bc = blockIdx.x;                    // (b*64+co)
    const int idx = amax[bc];
    const float4* tp = (const float4*)(tmpl + (size_t)idx * NPX);
    float4* yp = (float4*)(y + (size_t)bc * NPX);
    #pragma unroll 1
    for (int p = threadIdx.x; p < NPX / 4; p += 256) {
        float4 a = yp[p];
        float4 t = tp[p];
        a.x *= t.x; a.y *= t.y; a.z *= t.z; a.w *= t.w;
        a.x = a.x > 0.f ? a.x : 0.f;
        a.y = a.y > 0.f ? a.y : 0.f;
        a.z = a.z > 0.f ? a.z : 0.f;
        a.w = a.w > 0.f ? a.w : 0.f;
        yp[p] = a;
    }
}

extern "C" void kernel_launch(void* const* d_in, const int* in_sizes, int n_in,
                              void* d_out, int out_size, void* d_ws, size_t ws_size,
                              hipStream_t stream)
{
    (void)in_sizes; (void)n_in; (void)ws_size; (void)out_size;
    const float* x  = (const float*)d_in[0];
    const float* W  = (const float*)d_in[1];
    const float* bi = (const float*)d_in[2];
    const float* tm = (const float*)d_in[3];
    float* out = (float*)d_out;
    int*   amax = (int*)d_ws;                           // 32 KB
    float* w2   = (float*)((char*)d_ws + 32768);        // 72 KB

    hipLaunchKernelGGL(wtrans, dim3(72), dim3(256), 0, stream, W, w2);

    dim3 grid1(NB * (COUTN / CO_PB));   // 1024 blocks
    hipLaunchKernelGGL(conv_emul_pass1, grid1, dim3(THR), 0, stream,
                       x, w2, bi, out, amax);

    dim3 grid2(NB * COUTN);             // 8192 blocks
    hipLaunchKernelGGL(mask_apply_pass2, grid2, dim3(256), 0, stream,
                       out, tm, amax);
}

// Round 13
// 424.708 us; speedup vs baseline: 3.0960x; 1.9715x over previous
//
#include <hip/hip_runtime.h>
#include <cstddef>

#define NSP   56
#define NPX   3136
#define CINN  32
#define COUTN 64
#define NB    128
#define CO_PB 8
#define ROWS  7              // output rows per strip
#define NSTRIP 8             // 8 * 7 = 56
#define THR   448            // 7 waves; ty = wave = row-in-strip, tx<56 active
#define SROWS 9              // staged rows = ROWS + 2 halo
#define XCOL  68             // slots: 3 = left halo, 4..59 = cols 0..55, 60 = right halo

// ---- pass 0: transpose W [co][c][kh][kw] -> w2 [cog][kk][c][co8] ----
__global__ __launch_bounds__(256)
void wtrans(const float* __restrict__ W, float* __restrict__ w2)
{
    int idx = blockIdx.x * 256 + threadIdx.x;
    if (idx < COUTN * CINN * 9) {
        int co_l = idx & 7;
        int t    = idx >> 3;         // (cog*9 + kk)*32 + c
        int c    = t & 31;
        t >>= 5;                     // cog*9 + kk
        int kk   = t % 9;
        int cog  = t / 9;
        w2[idx] = W[(size_t)(cog * 8 + co_l) * (CINN * 9) + c * 9 + kk];
    }
}

// ---- pass 1: conv(+bias,relu) in XLA:CPU/Eigen rounding order, y + argmax ----
// Triple-buffered xv: LOAD(g+2) is WAR-pinned after FMA(g-1) -> every ds_read
// is >=2 FMA-groups (>=1024 cyc) older than any lgkmcnt drain that covers it.
__global__ __launch_bounds__(THR, 4)
void conv_emul_pass1(const float* __restrict__ x,
                     const float* __restrict__ w2,   // [8][9][32][8]
                     const float* __restrict__ bias,
                     float* __restrict__ y,          // d_out: relu(conv+bias)
                     int* __restrict__ amax)         // [NB*COUTN] argmax idx
{
    __shared__ float xs[SROWS][CINN][XCOL];
    __shared__ float rv[7][CO_PB];
    __shared__ int   ri[7][CO_PB];

    const int tid = threadIdx.x;
    const int ty  = tid >> 6;          // wave 0..6 = output row within strip
    const int tx  = tid & 63;          // active tx<56 in compute
    // cog-major-ish remap: co-resident blocks {i, i+256} and neighbors i,i+1
    // share cog -> the 9 KB weight slice stays K$/L2-hot.
    const int i   = blockIdx.x;
    const int cog = (i >> 5) & 7;
    const int b   = (i & 31) | ((i >> 8) << 5);
    const int co_base = cog * CO_PB;

    const float* xb = x  + (size_t)b * CINN * NPX;
    const float* wq = w2 + (size_t)cog * (9 * CINN * CO_PB);  // uniform

    // staging ownership: 448 = 32 channels x 14 float4-cols, fixed per thread
    const int sc = tid / 14;           // channel 0..31
    const int sv = tid - sc * 14;      // float4-col 0..13
    const float* xg = xb + (size_t)sc * NPX + 4 * sv;

    // halo columns (slots 3 and 60) are never written by staging: zero ONCE
    for (int t = tid; t < SROWS * CINN * 2; t += THR) {
        int rr  = t / (CINN * 2);
        int rem = t - rr * (CINN * 2);
        int c   = rem >> 1;
        xs[rr][c][(rem & 1) ? 60 : 3] = 0.f;
    }

    float bs[CO_PB];
    #pragma unroll
    for (int co = 0; co < CO_PB; ++co) bs[co] = bias[co_base + co];

    float v1[CO_PB]; int i1[CO_PB];
    #pragma unroll
    for (int co = 0; co < CO_PB; ++co) { v1[co] = -1.f; i1[co] = 0; }

    float* yo = y + (size_t)(b * COUTN + co_base) * NPX;

    #pragma unroll 1
    for (int g = 0; g < NSTRIP; ++g) {
        if (g) __syncthreads();        // WAR on xs

        // stage rows 7g-1 .. 7g+7 (9 rows): 9 float4 per thread, fixed ownership
        #pragma unroll
        for (int rr = 0; rr < SROWS; ++rr) {
            int gr = 7 * g + rr - 1;
            float4 val = make_float4(0.f, 0.f, 0.f, 0.f);
            if ((unsigned)gr < (unsigned)NSP)
                val = *(const float4*)(xg + gr * NSP);
            *(float4*)&xs[rr][sc][4 + 4 * sv] = val;
        }
        __syncthreads();

        float acc[CO_PB];
        #pragma unroll
        for (int co = 0; co < CO_PB; ++co) acc[co] = 0.f;

        if (tx < NSP) {
            // EXACT ref rounding order: groups gg = kh*3+kw processed 0..8,
            // c ascending within each group, single f32 acc, fmaf per term.
            float xv0[CINN], xv1[CINN], xv2[CINN];

#define LOADG(buf, gg) { \
            const int kh_ = (gg) / 3, kw_ = (gg) % 3; \
            _Pragma("unroll") \
            for (int c = 0; c < CINN; ++c) \
                buf[c] = xs[ty + kh_][c][tx + kw_ + 3]; }

#define FMAG(buf, gg) { \
            const float* wk_ = wq + (gg) * (CINN * CO_PB); \
            _Pragma("unroll") \
            for (int c = 0; c < CINN; ++c) { \
                _Pragma("unroll") \
                for (int co = 0; co < CO_PB; ++co) \
                    acc[co] = fmaf(buf[c], wk_[c * CO_PB + co], acc[co]); } }

            LOADG(xv0, 0); LOADG(xv1, 1);
            LOADG(xv2, 2); FMAG(xv0, 0);
            LOADG(xv0, 3); FMAG(xv1, 1);
            LOADG(xv1, 4); FMAG(xv2, 2);
            LOADG(xv2, 5); FMAG(xv0, 3);
            LOADG(xv0, 6); FMAG(xv1, 4);
            LOADG(xv1, 7); FMAG(xv2, 5);
            LOADG(xv2, 8); FMAG(xv0, 6);
            FMAG(xv1, 7);
            FMAG(xv2, 8);
#undef LOADG
#undef FMAG

            int p = (7 * g + ty) * NSP + tx;
            #pragma unroll
            for (int co = 0; co < CO_PB; ++co) {
                float v = acc[co] + bs[co];               // separate f32 add
                v = fmaxf(v, 0.f);
                yo[(size_t)co * NPX + p] = v;
                if (v > v1[co]) { v1[co] = v; i1[co] = p; }  // strict > = first idx
            }
        }
    }

    // block argmax per co: lexicographic (max val, min idx)
    #pragma unroll
    for (int co = 0; co < CO_PB; ++co) {
        float bv = v1[co]; int bi = i1[co];
        #pragma unroll
        for (int off = 32; off > 0; off >>= 1) {
            float ov = __shfl_xor(bv, off);
            int   oi = __shfl_xor(bi, off);
            if (ov > bv || (ov == bv && oi < bi)) { bv = ov; bi = oi; }
        }
        if ((tid & 63) == 0) { rv[ty][co] = bv; ri[ty][co] = bi; }
    }
    __syncthreads();
    if (tid < CO_PB) {
        float bv = rv[0][tid]; int bi = ri[0][tid];
        #pragma unroll
        for (int w = 1; w < 7; ++w) {
            float ov = rv[w][tid]; int oi = ri[w][tid];
            if (ov > bv || (ov == bv && oi < bi)) { bv = ov; bi = oi; }
        }
        amax[b * COUTN + co_base + tid] = bi;
    }
}

// ---- pass 2: in-place mask apply using the real templates input ----
__global__ __launch_bounds__(256)
void mask_apply_pass2(float* __restrict__ y,
                      const float* __restrict__ tmpl,
                      const int* __restrict__ amax)
{
    const int bc = blockIdx.x;                    // (b*64+co)
    const int idx = amax[bc];
    const float4* tp = (const float4*)(tmpl + (size_t)idx * NPX);
    float4* yp = (float4*)(y + (size_t)bc * NPX);
    #pragma unroll 1
    for (int p = threadIdx.x; p < NPX / 4; p += 256) {
        float4 a = yp[p];
        float4 t = tp[p];
        a.x *= t.x; a.y *= t.y; a.z *= t.z; a.w *= t.w;
        a.x = a.x > 0.f ? a.x : 0.f;
        a.y = a.y > 0.f ? a.y : 0.f;
        a.z = a.z > 0.f ? a.z : 0.f;
        a.w = a.w > 0.f ? a.w : 0.f;
        yp[p] = a;
    }
}

extern "C" void kernel_launch(void* const* d_in, const int* in_sizes, int n_in,
                              void* d_out, int out_size, void* d_ws, size_t ws_size,
                              hipStream_t stream)
{
    (void)in_sizes; (void)n_in; (void)ws_size; (void)out_size;
    const float* x  = (const float*)d_in[0];
    const float* W  = (const float*)d_in[1];
    const float* bi = (const float*)d_in[2];
    const float* tm = (const float*)d_in[3];
    float* out = (float*)d_out;
    int*   amax = (int*)d_ws;                           // 32 KB
    float* w2   = (float*)((char*)d_ws + 32768);        // 72 KB

    hipLaunchKernelGGL(wtrans, dim3(72), dim3(256), 0, stream, W, w2);

    dim3 grid1(NB * (COUTN / CO_PB));   // 1024 blocks
    hipLaunchKernelGGL(conv_emul_pass1, grid1, dim3(THR), 0, stream,
                       x, w2, bi, out, amax);

    dim3 grid2(NB * COUTN);             // 8192 blocks
    hipLaunchKernelGGL(mask_apply_pass2, grid2, dim3(256), 0, stream,
                       out, tm, amax);
}